// Round 23
// baseline (139.568 us; speedup 1.0000x reference)
//
#include <hip/hip_runtime.h>

#define NPOS   65536      // 16*16*16*16 positions
#define CDIM   256
#define KCODES 512
#define ZTOT   16777216   // 16*256*16*16*16
#define IDX_OFF (ZTOT + 1)
#define TAU    2.0e-3f
#define NC_FULL 0x7fff

// ws layout (float idx): [64..576)=cb_sq f32;
// [66112..131648) = cb bf16 fragment order (ushort[131072]);
// int nc[65536] @132096; float dold[65536] @197632; int cand[65536][8] @263168;
// float screen_partial[256] @787456; float refine_partial[2048] @787712
#define WS_CBSQ 64
#define WS_CBBF 66112
#define WS_NC   132096
#define WS_DOLD 197632
#define WS_CAND 263168
#define WS_SP   787456
#define WS_RP   787712

using bf16x8 = __attribute__((ext_vector_type(8))) short;
using f32x4  = __attribute__((ext_vector_type(4))) float;

// Raw barrier: wait LDS ops only; global loads/stores stay in flight.
#define BARLDS() do { \
    asm volatile("s_waitcnt lgkmcnt(0)" ::: "memory"); \
    __builtin_amdgcn_s_barrier(); \
    asm volatile("" ::: "memory"); \
} while (0)

__device__ __forceinline__ unsigned short f2bf(float f) {
    unsigned int u = __float_as_uint(f);
    return (unsigned short)((u + 0x7fffu + ((u >> 16) & 1u)) >> 16);
}

// Merged: fragment-order bf16 codebook (verified r8) + np-pairwise cb_sq
// (verified r3/r6). Block = one codebook row.
__global__ void vq_cvtprep(const float* __restrict__ cb, float* __restrict__ ws) {
    const int k = blockIdx.x;        // 512 blocks = codebook rows
    const int c = threadIdx.x;       // 256 channels
    __shared__ float row[256];
    __shared__ float chres[16];
    const float v = cb[(size_t)k * CDIM + c];
    row[c] = v;
    unsigned short* cbf2 = (unsigned short*)(ws + WS_CBBF);
    const int kt = c >> 5, g = (c & 31) >> 3, j = c & 7;
    cbf2[((((k >> 4) * 8 + kt) * 64) + g * 16 + (k & 15)) * 8 + j] = f2bf(v);
    __syncthreads();
    if (c < 16) {
        const float* a = &row[(c & 8) * 16];
        const int jj = c & 7;
        float r = __fmul_rn(a[jj], a[jj]);
        #pragma unroll 1
        for (int m = 1; m < 16; ++m)
            r = __fadd_rn(r, __fmul_rn(a[jj + 8 * m], a[jj + 8 * m]));
        chres[c] = r;
    }
    __syncthreads();
    if (c == 0) {
        float h0 = __fadd_rn(__fadd_rn(__fadd_rn(chres[0], chres[1]), __fadd_rn(chres[2], chres[3])),
                             __fadd_rn(__fadd_rn(chres[4], chres[5]), __fadd_rn(chres[6], chres[7])));
        float h1 = __fadd_rn(__fadd_rn(__fadd_rn(chres[8], chres[9]), __fadd_rn(chres[10], chres[11])),
                             __fadd_rn(__fadd_rn(chres[12], chres[13]), __fadd_rn(chres[14], chres[15])));
        ws[WS_CBSQ + k] = __fadd_rn(h0, h1);
    }
}

// A-tile staging write: channel c, quad q (positions q*4..q*4+3) -> frag LDS
__device__ __forceinline__ void stw(unsigned short A[2][8][64][8], int nb,
                                    int c, int q, float4 v) {
    const int kt = c >> 5, gg = (c & 31) >> 3, j = c & 7;
    unsigned short* d = &A[nb][kt][gg * 16 + q * 4][j];
    d[0]  = f2bf(v.x);
    d[8]  = f2bf(v.y);
    d[16] = f2bf(v.z);
    d[24] = f2bf(v.w);
}

// Screening v8: v3 core + PIPELINED EMIT. Per iter: [MFMA/argmin/red] B1
// [t<16: merge+out+emit(prev, via dbuf'd fv1/ccnt/candk in LDS); all: stw]
// B2 [rescan vs GLOBAL fv1 (v3 semantics — r20/21's wave-local rescan NOT
// repeated)]. Barriers 48->33, one serial phase/iter. Zero new register
// state (r12 spill lesson): dbuf state lives in LDS only.
__launch_bounds__(512, 2)
__global__ void vq_screen(const float* __restrict__ z,
                          float* __restrict__ ws,
                          float* __restrict__ out) {
    const int t  = threadIdx.x;
    const int w  = t >> 6;
    const int l  = t & 63;
    const int g  = l >> 4;
    const int c0 = l & 15;
    int* wsi = (int*)ws;
    const unsigned short* cbf2 = (const unsigned short*)(ws + WS_CBBF);

    __shared__ unsigned short ldsA[2][8][64][8];   // 16 KB (2 x 8 KB tiles)
    __shared__ float cbsq_s[KCODES];
    __shared__ float red_v[8][16];
    __shared__ int   red_i[8][16];
    __shared__ float fv1c[2][16];
    __shared__ int   ccnt[2][16];
    __shared__ int   candk[2][16][8];
    __shared__ float wls[8];

    cbsq_s[t] = ws[WS_CBSQ + t];       // 512 threads = 512 entries
    if (t < 32) ccnt[t >> 4][t & 15] = 0;

    // persistent B fragments: 4 code-groups x 8 kt = 128 regs, loaded once
    bf16x8 bfr[4][8];
    #pragma unroll
    for (int p = 0; p < 4; ++p)
        #pragma unroll
        for (int kt = 0; kt < 8; ++kt)
            bfr[p][kt] = *(const bf16x8*)(cbf2 + ((((w * 4 + p) * 8 + kt) * 64 + l) << 3));

    const int base = blockIdx.x * 256;                 // 256 rows per block
    const float* zB = z + (size_t)(base >> 12) * 1048576;
    const int c1 = t >> 2, q = t & 3;                  // staging role

    float lsq = 0.0f;       // exact f32 sum of z^2 over staged values
    float lsum = 0.0f;      // wave0 t<16: sum of row min scores

    // stage tile 0
    {
        const float* zb = zB + (base & 4095);
        float4 a0 = *(const float4*)(zb + (size_t)c1 * 4096 + q * 4);
        float4 a1 = *(const float4*)(zb + (size_t)(c1 + 128) * 4096 + q * 4);
        stw(ldsA, 0, c1, q, a0);
        stw(ldsA, 0, c1 + 128, q, a1);
        lsq += a0.x * a0.x + a0.y * a0.y + a0.z * a0.z + a0.w * a0.w;
        lsq += a1.x * a1.x + a1.y * a1.y + a1.z * a1.z + a1.w * a1.w;
    }
    __syncthreads();

    #pragma unroll 1
    for (int it = 0; it < 16; ++it) {
        const int buf = it & 1;
        const int m0  = base + it * 16;

        // issue next-tile A loads early (consumed by stw in the B1-B2 phase)
        float4 p0, p1;
        if (it < 15) {
            const float* zb = zB + ((m0 + 16) & 4095);
            p0 = *(const float4*)(zb + (size_t)c1 * 4096 + q * 4);
            p1 = *(const float4*)(zb + (size_t)(c1 + 128) * 4096 + q * 4);
        }

        f32x4 acc[4];
        #pragma unroll
        for (int p = 0; p < 4; ++p) acc[p] = (f32x4){0.f, 0.f, 0.f, 0.f};

        #pragma unroll
        for (int kt = 0; kt < 8; ++kt) {
            const bf16x8 a = *(const bf16x8*)&ldsA[buf][kt][l][0];
            acc[0] = __builtin_amdgcn_mfma_f32_16x16x32_bf16(a, bfr[0][kt], acc[0], 0, 0, 0);
            acc[1] = __builtin_amdgcn_mfma_f32_16x16x32_bf16(a, bfr[1][kt], acc[1], 0, 0, 0);
            acc[2] = __builtin_amdgcn_mfma_f32_16x16x32_bf16(a, bfr[2][kt], acc[2], 0, 0, 0);
            acc[3] = __builtin_amdgcn_mfma_f32_16x16x32_bf16(a, bfr[3][kt], acc[3], 0, 0, 0);
        }

        // per-lane argmin (k ascending via p), then 16-lane butterfly
        float v1[4]; int i1[4];
        #pragma unroll
        for (int r = 0; r < 4; ++r) { v1[r] = 3.4028235e38f; i1[r] = 0; }
        #pragma unroll
        for (int p = 0; p < 4; ++p) {
            const int k = w * 64 + p * 16 + c0;
            const float cq = cbsq_s[k];
            #pragma unroll
            for (int r = 0; r < 4; ++r) {
                const float s = fmaf(-2.0f, acc[p][r], cq);
                if (s < v1[r]) { v1[r] = s; i1[r] = k; }
            }
        }
        #pragma unroll
        for (int r = 0; r < 4; ++r) {
            #pragma unroll
            for (int m = 1; m < 16; m <<= 1) {
                float pv = __shfl_xor(v1[r], m, 64);
                int   pi = __shfl_xor(i1[r], m, 64);
                if (pv < v1[r] || (pv == v1[r] && pi < i1[r])) { v1[r] = pv; i1[r] = pi; }
            }
        }
        if (c0 == 0) {
            #pragma unroll
            for (int r = 0; r < 4; ++r) {
                red_v[w][g * 4 + r] = v1[r];
                red_i[w][g * 4 + r] = i1[r];
            }
        }
        BARLDS();                                      // B1

        if (t < 16) {
            // cross-wave merge (v3 semantics)
            float gv = red_v[0][t]; int gi = red_i[0][t];
            #pragma unroll
            for (int ww = 1; ww < 8; ++ww) {
                const float pv = red_v[ww][t];
                const int   pi = red_i[ww][t];
                if (pv < gv || (pv == gv && pi < gi)) { gv = pv; gi = pi; }
            }
            fv1c[buf][t] = gv;
            lsum += gv;
            out[IDX_OFF + m0 + t] = (float)gi;

            // pipelined emit of iteration it-1 (its rescan completed pre-B1)
            if (it > 0) {
                const int pb = buf ^ 1;
                const int np = m0 - 16 + t;
                const int nc = ccnt[pb][t];
                wsi[WS_NC + np] = (nc > 8) ? NC_FULL : nc;
                if (nc > 1) {
                    ws[WS_DOLD + np] = fv1c[pb][t];
                    #pragma unroll
                    for (int qq = 0; qq < 8; ++qq)
                        wsi[WS_CAND + np * 8 + qq] = (qq < nc && qq < 8) ? candk[pb][t][qq] : 0;
                }
                ccnt[pb][t] = 0;
            }
        }
        if (it < 15) {                                 // stw overlaps serial phase
            stw(ldsA, buf ^ 1, c1, q, p0);
            stw(ldsA, buf ^ 1, c1 + 128, q, p1);
            lsq += p0.x * p0.x + p0.y * p0.y + p0.z * p0.z + p0.w * p0.w;
            lsq += p1.x * p1.x + p1.y * p1.y + p1.z * p1.z + p1.w * p1.w;
        }
        BARLDS();                                      // B2

        // candidate rescan vs GLOBAL row-min (identical semantics to v3)
        #pragma unroll
        for (int p = 0; p < 4; ++p) {
            const int k = w * 64 + p * 16 + c0;
            const float cq = cbsq_s[k];
            #pragma unroll
            for (int r = 0; r < 4; ++r) {
                const float s = fmaf(-2.0f, acc[p][r], cq);
                const int row = g * 4 + r;
                if (s < fv1c[buf][row] + TAU) {
                    int pos = atomicAdd(&ccnt[buf][row], 1);
                    if (pos < 8) candk[buf][row][pos] = k;
                }
            }
        }
    }

    // drain: emit last iteration (rescan completed; barrier orders it)
    BARLDS();
    if (t < 16) {
        const int pb = 15 & 1;
        const int np = base + 15 * 16 + t;
        const int nc = ccnt[pb][t];
        wsi[WS_NC + np] = (nc > 8) ? NC_FULL : nc;
        if (nc > 1) {
            ws[WS_DOLD + np] = fv1c[pb][t];
            #pragma unroll
            for (int qq = 0; qq < 8; ++qq)
                wsi[WS_CAND + np * 8 + qq] = (qq < nc && qq < 8) ? candk[pb][t][qq] : 0;
        }
    }

    // block-end loss reduction -> dense partial (NO atomic, r19)
    #pragma unroll
    for (int m = 32; m > 0; m >>= 1)
        lsq += __shfl_down(lsq, m, 64);
    if (l == 0) wls[w] = lsq;
    #pragma unroll
    for (int m = 1; m < 16; m <<= 1)
        lsum += __shfl_xor(lsum, m, 64);    // lanes 0..15 of wave0
    __syncthreads();
    if (t == 0) {
        float tot = ((wls[0] + wls[1]) + (wls[2] + wls[3]))
                  + ((wls[4] + wls[5]) + (wls[6] + wls[7]));
        ws[WS_SP + blockIdx.x] = tot + lsum;
    }
}

// Refine v3 (r19, verbatim): window-batched, coalesced staging, dense
// loss partials — measured ~15 µs.
__launch_bounds__(256)
__global__ void vq_refine(const float* __restrict__ z,
                          const float* __restrict__ cb,
                          float* __restrict__ ws,
                          float* __restrict__ out) {
    const int t   = threadIdx.x;
    const int wid = t >> 6;
    const int l   = t & 63;
    int* wsi = (int*)ws;
    const int n0 = blockIdx.x * 32;

    __shared__ float zw[32][260];      // 33.3 KB, float4-aligned rows
    __shared__ int   snc[32];
    __shared__ float chres[32][16];
    __shared__ float zsq_s[32];
    __shared__ float wbv[4];
    __shared__ int   wbi[4];

    if (t < 32) snc[t] = wsi[WS_NC + n0 + t];

    const size_t zb = (size_t)(n0 >> 12) * 1048576 + (size_t)(n0 & 4095);
    const int rq = t & 7, ch = t >> 3;
    #pragma unroll
    for (int pass = 0; pass < 8; ++pass) {
        const int c = pass * 32 + ch;
        const float4 v = *(const float4*)(z + zb + (size_t)c * 4096 + rq * 4);
        zw[rq * 4 + 0][c] = v.x;
        zw[rq * 4 + 1][c] = v.y;
        zw[rq * 4 + 2][c] = v.z;
        zw[rq * 4 + 3][c] = v.w;
    }
    __syncthreads();

    {
        const int r = t >> 3, j = t & 7;
        #pragma unroll
        for (int h = 0; h < 2; ++h) {
            const float* a = &zw[r][h * 128];
            float rr = __fmul_rn(a[j], a[j]);
            #pragma unroll 1
            for (int m = 1; m < 16; ++m)
                rr = __fadd_rn(rr, __fmul_rn(a[j + 8 * m], a[j + 8 * m]));
            chres[r][h * 8 + j] = rr;
        }
    }
    __syncthreads();
    if (t < 32) {
        const float* cr = chres[t];
        float h0 = __fadd_rn(__fadd_rn(__fadd_rn(cr[0], cr[1]), __fadd_rn(cr[2], cr[3])),
                             __fadd_rn(__fadd_rn(cr[4], cr[5]), __fadd_rn(cr[6], cr[7])));
        float h1 = __fadd_rn(__fadd_rn(__fadd_rn(cr[8], cr[9]), __fadd_rn(cr[10], cr[11])),
                             __fadd_rn(__fadd_rn(cr[12], cr[13]), __fadd_rn(cr[14], cr[15])));
        zsq_s[t] = __fadd_rn(h0, h1);
    }
    __syncthreads();

    float bdelta = 0.0f;

    #pragma unroll 1
    for (int r = 0; r < 32; ++r) {
        const int nc = snc[r];
        if (nc <= 1) continue;
        const int n = n0 + r;
        const float zsq = zsq_s[r];
        const float4 zl = *(const float4*)&zw[r][4 * l];

        float bv = 3.4028235e38f;
        int   bi = 0x7fffffff;
        if (nc != NC_FULL) {
            for (int ci = wid; ci < nc; ci += 4) {
                const int k = wsi[WS_CAND + n * 8 + ci];
                const float4 e = *(const float4*)(cb + (size_t)k * CDIM + 4 * l);
                double d = (double)e.x * (double)zl.x + (double)e.y * (double)zl.y
                         + (double)e.z * (double)zl.z + (double)e.w * (double)zl.w;
                #pragma unroll
                for (int m = 1; m < 64; m <<= 1)
                    d += __shfl_xor(d, m, 64);
                const float dist = __fsub_rn(__fadd_rn(zsq, ws[WS_CBSQ + k]),
                                             __fmul_rn(2.0f, (float)d));
                if (dist < bv || (dist == bv && k < bi)) { bv = dist; bi = k; }
            }
        } else {
            for (int k = wid; k < KCODES; k += 4) {
                const float4 e = *(const float4*)(cb + (size_t)k * CDIM + 4 * l);
                double d = (double)e.x * (double)zl.x + (double)e.y * (double)zl.y
                         + (double)e.z * (double)zl.z + (double)e.w * (double)zl.w;
                #pragma unroll
                for (int m = 1; m < 64; m <<= 1)
                    d += __shfl_xor(d, m, 64);
                const float dist = __fsub_rn(__fadd_rn(zsq, ws[WS_CBSQ + k]),
                                             __fmul_rn(2.0f, (float)d));
                if (dist < bv || (dist == bv && k < bi)) { bv = dist; bi = k; }
            }
        }
        if (l == 0) { wbv[wid] = bv; wbi[wid] = bi; }
        __syncthreads();
        if (t == 0) {
            float v = wbv[0]; int i = wbi[0];
            #pragma unroll
            for (int ww = 1; ww < 4; ++ww) {
                if (wbv[ww] < v || (wbv[ww] == v && wbi[ww] < i)) { v = wbv[ww]; i = wbi[ww]; }
            }
            out[IDX_OFF + n] = (float)i;
            bdelta += (v - zsq) - ws[WS_DOLD + n];
        }
        __syncthreads();
    }

    if (t == 0) ws[WS_RP + blockIdx.x] = bdelta;
}

// z_q gather v3: WRITE-ONLY (loss comes from screen+refine distances).
__launch_bounds__(512)
__global__ void vq_gather(const float* __restrict__ cb,
                          float* __restrict__ out) {
    __shared__ int   sidx[64];
    __shared__ float lcb[64][257];     // 65.8 KB
    const int t  = threadIdx.x;
    const int n0 = blockIdx.x * 64;
    const int b  = n0 >> 12;
    const int s0 = n0 & 4095;

    if (t < 64) sidx[t] = (int)out[IDX_OFF + n0 + t];
    __syncthreads();

    {
        const int rlo = t & 7, q4 = t >> 3;
        #pragma unroll
        for (int i = 0; i < 8; ++i) {
            const int r = 8 * i + rlo;
            const float4 v = *(const float4*)(cb + (size_t)sidx[r] * CDIM + q4 * 4);
            lcb[r][q4 * 4 + 0] = v.x;
            lcb[r][q4 * 4 + 1] = v.y;
            lcb[r][q4 * 4 + 2] = v.z;
            lcb[r][q4 * 4 + 3] = v.w;
        }
    }
    __syncthreads();

    const int pq = t & 15, ch0 = t >> 4;
    const size_t obase = (size_t)b * 1048576 + (size_t)s0;
    #pragma unroll
    for (int pass = 0; pass < 8; ++pass) {
        const int c = pass * 32 + ch0;
        float4 v;
        v.x = lcb[pq * 4 + 0][c];
        v.y = lcb[pq * 4 + 1][c];
        v.z = lcb[pq * 4 + 2][c];
        v.w = lcb[pq * 4 + 3][c];
        *(float4*)(out + obase + (size_t)c * 4096 + pq * 4) = v;
    }
}

// Final: sum 256 screen partials + 2048 refine partials (deterministic tree)
__global__ void vq_fin(const float* __restrict__ ws, float* __restrict__ out) {
    __shared__ float red[512];
    const int t = threadIdx.x;
    float s = 0.0f;
    #pragma unroll
    for (int i = t; i < 2048; i += 512) s += ws[WS_RP + i];
    if (t < 256) s += ws[WS_SP + t];
    red[t] = s;
    __syncthreads();
    for (int off = 256; off > 0; off >>= 1) {
        if (t < off) red[t] += red[t + off];
        __syncthreads();
    }
    if (t == 0)
        out[ZTOT] = 1.25f * red[0] / (float)ZTOT;
}

extern "C" void kernel_launch(void* const* d_in, const int* in_sizes, int n_in,
                              void* d_out, int out_size, void* d_ws, size_t ws_size,
                              hipStream_t stream) {
    const float* z  = (const float*)d_in[0];
    const float* cb = (const float*)d_in[1];
    float* out = (float*)d_out;
    float* ws  = (float*)d_ws;

    vq_cvtprep<<<512, 256, 0, stream>>>(cb, ws);
    vq_screen<<<NPOS / 256, 512, 0, stream>>>(z, ws, out);
    vq_refine<<<NPOS / 32, 256, 0, stream>>>(z, cb, ws, out);
    vq_gather<<<NPOS / 64, 512, 0, stream>>>(cb, out);
    vq_fin<<<1, 512, 0, stream>>>(ws, out);
}

// Round 24
// 136.146 us; speedup vs baseline: 1.0251x; 1.0251x over previous
//
#include <hip/hip_runtime.h>

#define NPOS   65536      // 16*16*16*16 positions
#define CDIM   256
#define KCODES 512
#define ZTOT   16777216   // 16*256*16*16*16
#define IDX_OFF (ZTOT + 1)
#define TAU    2.0e-3f
#define NC_FULL 0x7fff

// ws layout (float idx): [64..576)=cb_sq f32;
// [66112..131648) = cb bf16 fragment order (ushort[131072]);
// int nc[65536] @132096; float dold[65536] @197632; int cand[65536][8] @263168;
// float screen_partial[256] @787456; float refine_partial[2048] @787712
#define WS_CBSQ 64
#define WS_CBBF 66112
#define WS_NC   132096
#define WS_DOLD 197632
#define WS_CAND 263168
#define WS_SP   787456
#define WS_RP   787712

using bf16x8 = __attribute__((ext_vector_type(8))) short;
using f32x4  = __attribute__((ext_vector_type(4))) float;

__device__ __forceinline__ unsigned short f2bf(float f) {
    unsigned int u = __float_as_uint(f);
    return (unsigned short)((u + 0x7fffu + ((u >> 16) & 1u)) >> 16);
}

// Merged: fragment-order bf16 codebook (verified r8) + np-pairwise cb_sq
// (verified r3/r6). Block = one codebook row.
__global__ void vq_cvtprep(const float* __restrict__ cb, float* __restrict__ ws) {
    const int k = blockIdx.x;        // 512 blocks = codebook rows
    const int c = threadIdx.x;       // 256 channels
    __shared__ float row[256];
    __shared__ float chres[16];
    const float v = cb[(size_t)k * CDIM + c];
    row[c] = v;
    unsigned short* cbf2 = (unsigned short*)(ws + WS_CBBF);
    const int kt = c >> 5, g = (c & 31) >> 3, j = c & 7;
    cbf2[((((k >> 4) * 8 + kt) * 64) + g * 16 + (k & 15)) * 8 + j] = f2bf(v);
    __syncthreads();
    if (c < 16) {
        const float* a = &row[(c & 8) * 16];
        const int jj = c & 7;
        float r = __fmul_rn(a[jj], a[jj]);
        #pragma unroll 1
        for (int m = 1; m < 16; ++m)
            r = __fadd_rn(r, __fmul_rn(a[jj + 8 * m], a[jj + 8 * m]));
        chres[c] = r;
    }
    __syncthreads();
    if (c == 0) {
        float h0 = __fadd_rn(__fadd_rn(__fadd_rn(chres[0], chres[1]), __fadd_rn(chres[2], chres[3])),
                             __fadd_rn(__fadd_rn(chres[4], chres[5]), __fadd_rn(chres[6], chres[7])));
        float h1 = __fadd_rn(__fadd_rn(__fadd_rn(chres[8], chres[9]), __fadd_rn(chres[10], chres[11])),
                             __fadd_rn(__fadd_rn(chres[12], chres[13]), __fadd_rn(chres[14], chres[15])));
        ws[WS_CBSQ + k] = __fadd_rn(h0, h1);
    }
}

// A-tile staging write: channel c, quad q (positions q*4..q*4+3) -> frag LDS
__device__ __forceinline__ void stw(unsigned short A[2][8][64][8], int nb,
                                    int c, int q, float4 v) {
    const int kt = c >> 5, gg = (c & 31) >> 3, j = c & 7;
    unsigned short* d = &A[nb][kt][gg * 16 + q * 4][j];
    d[0]  = f2bf(v.x);
    d[8]  = f2bf(v.y);
    d[16] = f2bf(v.z);
    d[24] = f2bf(v.w);
}

// Screening v3 core (measured 80 µs plateau across 5 schedule variants —
// register-capped at 2 waves/SIMD with persistent-B; do not restructure)
// + fused loss via dense per-block partial (r19). Dense candidate arrays.
__launch_bounds__(512, 2)
__global__ void vq_screen(const float* __restrict__ z,
                          float* __restrict__ ws,
                          float* __restrict__ out) {
    const int t  = threadIdx.x;
    const int w  = t >> 6;
    const int l  = t & 63;
    const int g  = l >> 4;
    const int c0 = l & 15;
    int* wsi = (int*)ws;
    const unsigned short* cbf2 = (const unsigned short*)(ws + WS_CBBF);

    __shared__ unsigned short ldsA[2][8][64][8];   // 16 KB (2 x 8 KB tiles)
    __shared__ float cbsq_s[KCODES];
    __shared__ float red_v[8][16];
    __shared__ int   red_i[8][16];
    __shared__ float fv1[16];
    __shared__ int   ccnt[16];
    __shared__ int   candk[16][8];
    __shared__ float wls[8];

    cbsq_s[t] = ws[WS_CBSQ + t];       // 512 threads = 512 entries
    if (t < 16) ccnt[t] = 0;

    // persistent B fragments: 4 code-groups x 8 kt = 128 regs, loaded once
    bf16x8 bfr[4][8];
    #pragma unroll
    for (int p = 0; p < 4; ++p)
        #pragma unroll
        for (int kt = 0; kt < 8; ++kt)
            bfr[p][kt] = *(const bf16x8*)(cbf2 + ((((w * 4 + p) * 8 + kt) * 64 + l) << 3));

    const int base = blockIdx.x * 256;                 // 256 rows per block
    const float* zB = z + (size_t)(base >> 12) * 1048576;
    const int c1 = t >> 2, q = t & 3;                  // staging role

    float lsq = 0.0f;       // exact f32 sum of z^2 over staged values
    float lsum = 0.0f;      // wave0 t<16: sum of row min scores

    // stage tile 0
    {
        const float* zb = zB + (base & 4095);
        float4 a0 = *(const float4*)(zb + (size_t)c1 * 4096 + q * 4);
        float4 a1 = *(const float4*)(zb + (size_t)(c1 + 128) * 4096 + q * 4);
        stw(ldsA, 0, c1, q, a0);
        stw(ldsA, 0, c1 + 128, q, a1);
        lsq += a0.x * a0.x + a0.y * a0.y + a0.z * a0.z + a0.w * a0.w;
        lsq += a1.x * a1.x + a1.y * a1.y + a1.z * a1.z + a1.w * a1.w;
    }
    __syncthreads();

    #pragma unroll 1
    for (int it = 0; it < 16; ++it) {
        const int buf = it & 1;
        const int m0  = base + it * 16;

        // issue next-tile A loads early (consumed by stw before B3)
        float4 p0, p1;
        if (it < 15) {
            const float* zb = zB + ((m0 + 16) & 4095);
            p0 = *(const float4*)(zb + (size_t)c1 * 4096 + q * 4);
            p1 = *(const float4*)(zb + (size_t)(c1 + 128) * 4096 + q * 4);
        }

        f32x4 acc[4];
        #pragma unroll
        for (int p = 0; p < 4; ++p) acc[p] = (f32x4){0.f, 0.f, 0.f, 0.f};

        #pragma unroll
        for (int kt = 0; kt < 8; ++kt) {
            const bf16x8 a = *(const bf16x8*)&ldsA[buf][kt][l][0];
            acc[0] = __builtin_amdgcn_mfma_f32_16x16x32_bf16(a, bfr[0][kt], acc[0], 0, 0, 0);
            acc[1] = __builtin_amdgcn_mfma_f32_16x16x32_bf16(a, bfr[1][kt], acc[1], 0, 0, 0);
            acc[2] = __builtin_amdgcn_mfma_f32_16x16x32_bf16(a, bfr[2][kt], acc[2], 0, 0, 0);
            acc[3] = __builtin_amdgcn_mfma_f32_16x16x32_bf16(a, bfr[3][kt], acc[3], 0, 0, 0);
        }

        // per-lane argmin (k ascending via p), then 16-lane butterfly
        float v1[4]; int i1[4];
        #pragma unroll
        for (int r = 0; r < 4; ++r) { v1[r] = 3.4028235e38f; i1[r] = 0; }
        #pragma unroll
        for (int p = 0; p < 4; ++p) {
            const int k = w * 64 + p * 16 + c0;
            const float cq = cbsq_s[k];
            #pragma unroll
            for (int r = 0; r < 4; ++r) {
                const float s = fmaf(-2.0f, acc[p][r], cq);
                if (s < v1[r]) { v1[r] = s; i1[r] = k; }
            }
        }
        #pragma unroll
        for (int r = 0; r < 4; ++r) {
            #pragma unroll
            for (int m = 1; m < 16; m <<= 1) {
                float pv = __shfl_xor(v1[r], m, 64);
                int   pi = __shfl_xor(i1[r], m, 64);
                if (pv < v1[r] || (pv == v1[r] && pi < i1[r])) { v1[r] = pv; i1[r] = pi; }
            }
        }
        if (c0 == 0) {
            #pragma unroll
            for (int r = 0; r < 4; ++r) {
                red_v[w][g * 4 + r] = v1[r];
                red_i[w][g * 4 + r] = i1[r];
            }
        }
        __syncthreads();                               // B1

        if (t < 16) {
            float gv = red_v[0][t]; int gi = red_i[0][t];
            #pragma unroll
            for (int ww = 1; ww < 8; ++ww) {
                const float pv = red_v[ww][t];
                const int   pi = red_i[ww][t];
                if (pv < gv || (pv == gv && pi < gi)) { gv = pv; gi = pi; }
            }
            fv1[t] = gv;
            lsum += gv;                                // loss base (score scale)
            out[IDX_OFF + m0 + t] = (float)gi;         // provisional/final
        }
        __syncthreads();                               // B2

        // candidate rescan vs global row-min (verified semantics)
        #pragma unroll
        for (int p = 0; p < 4; ++p) {
            const int k = w * 64 + p * 16 + c0;
            const float cq = cbsq_s[k];
            #pragma unroll
            for (int r = 0; r < 4; ++r) {
                const float s = fmaf(-2.0f, acc[p][r], cq);
                const int row = g * 4 + r;
                if (s < fv1[row] + TAU) {
                    int pos = atomicAdd(&ccnt[row], 1);
                    if (pos < 8) candk[row][pos] = k;
                }
            }
        }
        if (it < 15) {                                 // land next A tile
            stw(ldsA, buf ^ 1, c1, q, p0);
            stw(ldsA, buf ^ 1, c1 + 128, q, p1);
            lsq += p0.x * p0.x + p0.y * p0.y + p0.z * p0.z + p0.w * p0.w;
            lsq += p1.x * p1.x + p1.y * p1.y + p1.z * p1.z + p1.w * p1.w;
        }
        __syncthreads();                               // B3

        if (t < 16) {
            const int nc = ccnt[t];
            const int n  = m0 + t;
            wsi[WS_NC + n] = (nc > 8) ? NC_FULL : nc;
            if (nc > 1) {
                ws[WS_DOLD + n] = fv1[t];
                #pragma unroll
                for (int qq = 0; qq < 8; ++qq)
                    wsi[WS_CAND + n * 8 + qq] = (qq < nc && qq < 8) ? candk[t][qq] : 0;
            }
            ccnt[t] = 0;
        }
    }

    // block-end loss reduction -> dense partial (NO atomic; r18 lesson:
    // same-address device atomics cost ~10.6 µs per 1000)
    #pragma unroll
    for (int m = 32; m > 0; m >>= 1)
        lsq += __shfl_down(lsq, m, 64);
    if (l == 0) wls[w] = lsq;
    #pragma unroll
    for (int m = 1; m < 16; m <<= 1)
        lsum += __shfl_xor(lsum, m, 64);    // lanes 0..15 of wave0
    __syncthreads();
    if (t == 0) {
        float tot = ((wls[0] + wls[1]) + (wls[2] + wls[3]))
                  + ((wls[4] + wls[5]) + (wls[6] + wls[7]));
        ws[WS_SP + blockIdx.x] = tot + lsum;
    }
}

// Refine v3 (r19): window-batched, coalesced staging, dense loss partials.
__launch_bounds__(256)
__global__ void vq_refine(const float* __restrict__ z,
                          const float* __restrict__ cb,
                          float* __restrict__ ws,
                          float* __restrict__ out) {
    const int t   = threadIdx.x;
    const int wid = t >> 6;
    const int l   = t & 63;
    int* wsi = (int*)ws;
    const int n0 = blockIdx.x * 32;

    __shared__ float zw[32][260];      // 33.3 KB, float4-aligned rows
    __shared__ int   snc[32];
    __shared__ float chres[32][16];
    __shared__ float zsq_s[32];
    __shared__ float wbv[4];
    __shared__ int   wbi[4];

    if (t < 32) snc[t] = wsi[WS_NC + n0 + t];

    // coalesced window stage: lane reads 16B quad (8 full lines/instruction)
    const size_t zb = (size_t)(n0 >> 12) * 1048576 + (size_t)(n0 & 4095);
    const int rq = t & 7, ch = t >> 3;        // pos-quad 0..7, channel 0..31
    #pragma unroll
    for (int pass = 0; pass < 8; ++pass) {
        const int c = pass * 32 + ch;
        const float4 v = *(const float4*)(z + zb + (size_t)c * 4096 + rq * 4);
        zw[rq * 4 + 0][c] = v.x;
        zw[rq * 4 + 1][c] = v.y;
        zw[rq * 4 + 2][c] = v.z;
        zw[rq * 4 + 3][c] = v.w;
    }
    __syncthreads();

    // np-pairwise zsq, all rows parallel: thread = (row t>>3, chain t&7)
    {
        const int r = t >> 3, j = t & 7;
        #pragma unroll
        for (int h = 0; h < 2; ++h) {
            const float* a = &zw[r][h * 128];
            float rr = __fmul_rn(a[j], a[j]);
            #pragma unroll 1
            for (int m = 1; m < 16; ++m)
                rr = __fadd_rn(rr, __fmul_rn(a[j + 8 * m], a[j + 8 * m]));
            chres[r][h * 8 + j] = rr;
        }
    }
    __syncthreads();
    if (t < 32) {
        const float* cr = chres[t];
        float h0 = __fadd_rn(__fadd_rn(__fadd_rn(cr[0], cr[1]), __fadd_rn(cr[2], cr[3])),
                             __fadd_rn(__fadd_rn(cr[4], cr[5]), __fadd_rn(cr[6], cr[7])));
        float h1 = __fadd_rn(__fadd_rn(__fadd_rn(cr[8], cr[9]), __fadd_rn(cr[10], cr[11])),
                             __fadd_rn(__fadd_rn(cr[12], cr[13]), __fadd_rn(cr[14], cr[15])));
        zsq_s[t] = __fadd_rn(h0, h1);
    }
    __syncthreads();

    float bdelta = 0.0f;      // thread 0 only: window loss delta

    #pragma unroll 1
    for (int r = 0; r < 32; ++r) {
        const int nc = snc[r];                 // LDS: wave-uniform branch
        if (nc <= 1) continue;
        const int n = n0 + r;
        const float zsq = zsq_s[r];
        const float4 zl = *(const float4*)&zw[r][4 * l];

        float bv = 3.4028235e38f;
        int   bi = 0x7fffffff;
        if (nc != NC_FULL) {
            for (int ci = wid; ci < nc; ci += 4) {
                const int k = wsi[WS_CAND + n * 8 + ci];
                const float4 e = *(const float4*)(cb + (size_t)k * CDIM + 4 * l);
                double d = (double)e.x * (double)zl.x + (double)e.y * (double)zl.y
                         + (double)e.z * (double)zl.z + (double)e.w * (double)zl.w;
                #pragma unroll
                for (int m = 1; m < 64; m <<= 1)
                    d += __shfl_xor(d, m, 64);
                const float dist = __fsub_rn(__fadd_rn(zsq, ws[WS_CBSQ + k]),
                                             __fmul_rn(2.0f, (float)d));
                if (dist < bv || (dist == bv && k < bi)) { bv = dist; bi = k; }
            }
        } else {
            for (int k = wid; k < KCODES; k += 4) {
                const float4 e = *(const float4*)(cb + (size_t)k * CDIM + 4 * l);
                double d = (double)e.x * (double)zl.x + (double)e.y * (double)zl.y
                         + (double)e.z * (double)zl.z + (double)e.w * (double)zl.w;
                #pragma unroll
                for (int m = 1; m < 64; m <<= 1)
                    d += __shfl_xor(d, m, 64);
                const float dist = __fsub_rn(__fadd_rn(zsq, ws[WS_CBSQ + k]),
                                             __fmul_rn(2.0f, (float)d));
                if (dist < bv || (dist == bv && k < bi)) { bv = dist; bi = k; }
            }
        }
        if (l == 0) { wbv[wid] = bv; wbi[wid] = bi; }
        __syncthreads();
        if (t == 0) {
            float v = wbv[0]; int i = wbi[0];
            #pragma unroll
            for (int ww = 1; ww < 4; ++ww) {
                if (wbv[ww] < v || (wbv[ww] == v && wbi[ww] < i)) { v = wbv[ww]; i = wbi[ww]; }
            }
            out[IDX_OFF + n] = (float)i;
            bdelta += (v - zsq) - ws[WS_DOLD + n];   // accumulate, no atomic
        }
        __syncthreads();
    }

    if (t == 0) ws[WS_RP + blockIdx.x] = bdelta;     // dense partial
}

// z_q gather v3: WRITE-ONLY (loss comes from screen+refine distances).
__launch_bounds__(512)
__global__ void vq_gather(const float* __restrict__ cb,
                          float* __restrict__ out) {
    __shared__ int   sidx[64];
    __shared__ float lcb[64][257];     // 65.8 KB
    const int t  = threadIdx.x;
    const int n0 = blockIdx.x * 64;
    const int b  = n0 >> 12;
    const int s0 = n0 & 4095;

    if (t < 64) sidx[t] = (int)out[IDX_OFF + n0 + t];
    __syncthreads();

    {
        const int rlo = t & 7, q4 = t >> 3;
        #pragma unroll
        for (int i = 0; i < 8; ++i) {
            const int r = 8 * i + rlo;
            const float4 v = *(const float4*)(cb + (size_t)sidx[r] * CDIM + q4 * 4);
            lcb[r][q4 * 4 + 0] = v.x;
            lcb[r][q4 * 4 + 1] = v.y;
            lcb[r][q4 * 4 + 2] = v.z;
            lcb[r][q4 * 4 + 3] = v.w;
        }
    }
    __syncthreads();

    const int pq = t & 15, ch0 = t >> 4;    // 16 pos-quads x 32 ch-groups
    const size_t obase = (size_t)b * 1048576 + (size_t)s0;
    #pragma unroll
    for (int pass = 0; pass < 8; ++pass) {
        const int c = pass * 32 + ch0;
        float4 v;
        v.x = lcb[pq * 4 + 0][c];
        v.y = lcb[pq * 4 + 1][c];
        v.z = lcb[pq * 4 + 2][c];
        v.w = lcb[pq * 4 + 3][c];
        *(float4*)(out + obase + (size_t)c * 4096 + pq * 4) = v;
    }
}

// Final: sum 256 screen partials + 2048 refine partials (deterministic tree)
__global__ void vq_fin(const float* __restrict__ ws, float* __restrict__ out) {
    __shared__ float red[512];
    const int t = threadIdx.x;
    float s = 0.0f;
    #pragma unroll
    for (int i = t; i < 2048; i += 512) s += ws[WS_RP + i];
    if (t < 256) s += ws[WS_SP + t];
    red[t] = s;
    __syncthreads();
    for (int off = 256; off > 0; off >>= 1) {
        if (t < off) red[t] += red[t + off];
        __syncthreads();
    }
    if (t == 0)
        out[ZTOT] = 1.25f * red[0] / (float)ZTOT;
}

extern "C" void kernel_launch(void* const* d_in, const int* in_sizes, int n_in,
                              void* d_out, int out_size, void* d_ws, size_t ws_size,
                              hipStream_t stream) {
    const float* z  = (const float*)d_in[0];
    const float* cb = (const float*)d_in[1];
    float* out = (float*)d_out;
    float* ws  = (float*)d_ws;

    vq_cvtprep<<<512, 256, 0, stream>>>(cb, ws);
    vq_screen<<<NPOS / 256, 512, 0, stream>>>(z, ws, out);
    vq_refine<<<NPOS / 32, 256, 0, stream>>>(z, cb, ws, out);
    vq_gather<<<NPOS / 64, 512, 0, stream>>>(cb, out);
    vq_fin<<<1, 512, 0, stream>>>(ws, out);
}